// Round 11
// baseline (165.525 us; speedup 1.0000x reference)
//
#include <hip/hip_runtime.h>
#include <hip/hip_bf16.h>

#define FEATSZ 2048
#define HIDSZ  1024
#define ATTSZ  512
#define BATCH  64
#define FEATN  512

typedef float  f32x4  __attribute__((ext_vector_type(4)));
typedef __bf16 bf16x8 __attribute__((ext_vector_type(8)));

__device__ __forceinline__ unsigned short f2bf(float f) {
    union { float f; unsigned int u; } x; x.f = f;
    unsigned int u = x.u;
    return (unsigned short)((u + 0x7fffu + ((u >> 16) & 1u)) >> 16);
}

// ---------------- K0a: h = key @ wh_w.T + wh_b  (64 x 512) ----------------
__global__ void k_h(const float* __restrict__ key, const float* __restrict__ wh_w,
                    const float* __restrict__ wh_b, float* __restrict__ h) {
    const int b = blockIdx.y;
    const int ac = blockIdx.x;
    const int t = threadIdx.x;         // 256
    const int lane = t & 63, wv = t >> 6;
    float k16[16];
    const float* kb = key + b * HIDSZ;
#pragma unroll
    for (int j = 0; j < 16; ++j) k16[j] = kb[lane + 64 * j];
#pragma unroll 1
    for (int i = 0; i < 16; ++i) {
        int a = ac * 64 + wv * 16 + i;
        const float* wr = wh_w + (size_t)a * HIDSZ;
        float s = 0.f;
#pragma unroll
        for (int j = 0; j < 16; ++j) s += k16[j] * wr[lane + 64 * j];
#pragma unroll
        for (int d = 32; d; d >>= 1) s += __shfl_xor(s, d);
        if (lane == 0) h[b * ATTSZ + a] = s + wh_b[a];
    }
}

// ------- K0b: convert wv_w (512x2048 f32) -> bf16 in MFMA-fragment order -------
// frag (kk, CF) = 1024B at (kk*32+CF)*1024; lane l holds 16B (8 bf16) at +l*16.
__global__ void k_wvcvt(const float* __restrict__ wv_w, unsigned short* __restrict__ wvb) {
    int idx = blockIdx.x * 256 + threadIdx.x;       // < 512*2048
    int a = idx >> 11, k = idx & 2047;
    int CF = a >> 4, c = a & 15, ks = k >> 5, kin = k & 31;
    int lane = c + ((kin >> 3) << 4);
    int dst = ((ks * 32 + CF) * 64 + lane) * 8 + (kin & 7);
    wvb[dst] = f2bf(wv_w[idx]);
}

// ---------------- K1: fused GEMM(feats, wv^T) + tanh·wa -> partial scores -------
// m201-style 8-phase port: 256 blocks (1/CU), 512 thr = 8 waves (2M x 4N).
// BM=256 x BN=256 (nt=bx&1) x BK=64, 32 K-tiles x 4 phases, ONE barrier/K-tile.
// A: fp32 glb->reg (issued at tile kt for kt+2: full-tile cover) -> bf16 cvt ->
// XOR-(row&7)-swizzled ds_write (conflict-free write AND read). B: L2-resident
// frag-ordered wvb, reg ping-pong loaded 2 phases early. 16 MFMA per phase.
__global__ __launch_bounds__(512) void k_scores(
        const float* __restrict__ feats, const unsigned short* __restrict__ wvb,
        const float* __restrict__ h, const float* __restrict__ wv_b,
        const float* __restrict__ wa, float* __restrict__ part_sc) {
    __shared__ __align__(16) char Abuf[2][32768];   // [buf][256 rows][64 k] bf16 swizzled
    __shared__ float scp[4][256];
    const int t = threadIdx.x, lane = t & 63, w = t >> 6;
    const int wm = w >> 2, wn = w & 3;
    const int mb = blockIdx.x >> 1, nt = blockIdx.x & 1;
    const int m0 = mb * 256, b = blockIdx.x >> 2;

    // ---- staging consts: thread covers row (p*64 + (t>>3)), chunk c=t&7 (8 bf16)
    const float* gbase = feats + (size_t)(m0 + (t >> 3)) * FEATSZ + (t & 7) * 8;
    const int woff = ((t >> 3) * 128) + ((((t & 7) ^ ((t >> 3) & 7))) * 16);

    // ---- B base: CF = nt*16 + wn*4 + cf
    const unsigned short* wbase = wvb + (size_t)(nt * 16 + wn * 4) * 512 + lane * 8;

    // ---- A-frag read consts: row = wm*128 + m*16 + (lane&15)
    const int arow = wm * 128 + (lane & 15);
    const int aq = lane >> 4, ax = lane & 7;

    f32x4 acc[8][4];
#pragma unroll
    for (int m = 0; m < 8; ++m)
#pragma unroll
        for (int cf = 0; cf < 4; ++cf) acc[m][cf] = (f32x4)0.0f;

    bf16x8 BA[4], BB[4];
    f32x4 G0a, G0b, G1a, G1b, G2a, G2b, G3a, G3b;

    auto issueG = [&](int kt, int p, f32x4& ga, f32x4& gb) {
        const float* s = gbase + (size_t)p * (64 * FEATSZ) + kt * 64;
        ga = *(const f32x4*)s;
        gb = *(const f32x4*)(s + 4);
    };
    auto loadB = [&](bf16x8(&B)[4], int kkg) {
#pragma unroll
        for (int cf = 0; cf < 4; ++cf)
            B[cf] = *(const bf16x8*)(wbase + (size_t)(kkg * 32 + cf) * 512);
    };
    auto cvtWrite = [&](char* bw, int p, f32x4 ga, f32x4 gb) {
        bf16x8 v;
        v[0] = (__bf16)ga[0]; v[1] = (__bf16)ga[1]; v[2] = (__bf16)ga[2]; v[3] = (__bf16)ga[3];
        v[4] = (__bf16)gb[0]; v[5] = (__bf16)gb[1]; v[6] = (__bf16)gb[2]; v[7] = (__bf16)gb[3];
        *(bf16x8*)__builtin_assume_aligned(bw + p * 8192 + woff, 16) = v;
    };
    auto mfmaPhase = [&](const char* br, int mg, int kk, bf16x8(&B)[4]) {
        bf16x8 a0 = *(const bf16x8*)__builtin_assume_aligned(br + (arow + (mg + 0) * 16) * 128 + (((kk * 4 + aq) ^ ax) * 16), 16);
        bf16x8 a1 = *(const bf16x8*)__builtin_assume_aligned(br + (arow + (mg + 1) * 16) * 128 + (((kk * 4 + aq) ^ ax) * 16), 16);
        bf16x8 a2 = *(const bf16x8*)__builtin_assume_aligned(br + (arow + (mg + 2) * 16) * 128 + (((kk * 4 + aq) ^ ax) * 16), 16);
        bf16x8 a3 = *(const bf16x8*)__builtin_assume_aligned(br + (arow + (mg + 3) * 16) * 128 + (((kk * 4 + aq) ^ ax) * 16), 16);
        __builtin_amdgcn_s_setprio(1);
#pragma unroll
        for (int cf = 0; cf < 4; ++cf) acc[mg + 0][cf] = __builtin_amdgcn_mfma_f32_16x16x32_bf16(a0, B[cf], acc[mg + 0][cf], 0, 0, 0);
#pragma unroll
        for (int cf = 0; cf < 4; ++cf) acc[mg + 1][cf] = __builtin_amdgcn_mfma_f32_16x16x32_bf16(a1, B[cf], acc[mg + 1][cf], 0, 0, 0);
#pragma unroll
        for (int cf = 0; cf < 4; ++cf) acc[mg + 2][cf] = __builtin_amdgcn_mfma_f32_16x16x32_bf16(a2, B[cf], acc[mg + 2][cf], 0, 0, 0);
#pragma unroll
        for (int cf = 0; cf < 4; ++cf) acc[mg + 3][cf] = __builtin_amdgcn_mfma_f32_16x16x32_bf16(a3, B[cf], acc[mg + 3][cf], 0, 0, 0);
        __builtin_amdgcn_s_setprio(0);
        __builtin_amdgcn_sched_barrier(0);
    };

    // ---- prologue: tile 0 into buf0; issue tile 1 regs; B(kt0,kk0)
    issueG(0, 0, G0a, G0b); issueG(0, 1, G1a, G1b);
    issueG(0, 2, G2a, G2b); issueG(0, 3, G3a, G3b);
    loadB(BA, 0);
    cvtWrite(&Abuf[0][0], 0, G0a, G0b);
    cvtWrite(&Abuf[0][0], 1, G1a, G1b);
    cvtWrite(&Abuf[0][0], 2, G2a, G2b);
    cvtWrite(&Abuf[0][0], 3, G3a, G3b);
    issueG(1, 0, G0a, G0b); issueG(1, 1, G1a, G1b);
    issueG(1, 2, G2a, G2b); issueG(1, 3, G3a, G3b);
    __syncthreads();

#pragma unroll 1
    for (int kt = 0; kt < 32; ++kt) {
        const char* br = &Abuf[kt & 1][0];
        char* bw = &Abuf[(kt & 1) ^ 1][0];
        // phase 0: BB <- (kt, kk1); write (kt+1,0); issue (kt+2,0); MFMA m0-3 kk0
        loadB(BB, kt * 2 + 1);
        if (kt < 31) cvtWrite(bw, 0, G0a, G0b);
        if (kt < 30) issueG(kt + 2, 0, G0a, G0b);
        mfmaPhase(br, 0, 0, BA);
        // phase 1: write (kt+1,1); issue (kt+2,1); MFMA m4-7 kk0
        if (kt < 31) cvtWrite(bw, 1, G1a, G1b);
        if (kt < 30) issueG(kt + 2, 1, G1a, G1b);
        mfmaPhase(br, 4, 0, BA);
        // phase 2: BA <- (kt+1, kk0); write (kt+1,2); issue (kt+2,2); MFMA m0-3 kk1
        if (kt < 31) loadB(BA, (kt + 1) * 2);
        if (kt < 31) cvtWrite(bw, 2, G2a, G2b);
        if (kt < 30) issueG(kt + 2, 2, G2a, G2b);
        mfmaPhase(br, 0, 1, BB);
        // phase 3: write (kt+1,3); issue (kt+2,3); MFMA m4-7 kk1
        if (kt < 31) cvtWrite(bw, 3, G3a, G3b);
        if (kt < 30) issueG(kt + 2, 3, G3a, G3b);
        mfmaPhase(br, 4, 1, BB);
        // one barrier per K-tile
        asm volatile("s_waitcnt lgkmcnt(0)" ::: "memory");
        __builtin_amdgcn_s_barrier();
        __builtin_amdgcn_sched_barrier(0);
    }

    // ---- epilogue: partial score over this block's 256 cols
    const int c16 = lane & 15, q4 = lane >> 4;
    float hreg[4], wreg[4];
#pragma unroll
    for (int cf = 0; cf < 4; ++cf) {
        int a = nt * 256 + wn * 64 + cf * 16 + c16;
        hreg[cf] = h[b * ATTSZ + a] + wv_b[a];
        wreg[cf] = wa[a];
    }
    float pv[8][4];
#pragma unroll
    for (int m = 0; m < 8; ++m)
#pragma unroll
        for (int jr = 0; jr < 4; ++jr) pv[m][jr] = 0.f;
#pragma unroll
    for (int m = 0; m < 8; ++m)
#pragma unroll
        for (int cf = 0; cf < 4; ++cf)
#pragma unroll
            for (int jr = 0; jr < 4; ++jr)
                pv[m][jr] += tanhf(acc[m][cf][jr] + hreg[cf]) * wreg[cf];
#pragma unroll
    for (int m = 0; m < 8; ++m)
#pragma unroll
        for (int jr = 0; jr < 4; ++jr) {
            float v = pv[m][jr];
            v += __shfl_xor(v, 1); v += __shfl_xor(v, 2);
            v += __shfl_xor(v, 4); v += __shfl_xor(v, 8);
            pv[m][jr] = v;
        }
    if (c16 == 0) {
#pragma unroll
        for (int m = 0; m < 8; ++m)
#pragma unroll
            for (int jr = 0; jr < 4; ++jr)
                scp[wn][wm * 128 + m * 16 + q4 * 4 + jr] = pv[m][jr];
    }
    __syncthreads();
    if (t < 256)
        part_sc[nt * (BATCH * FEATN) + m0 + t]
            = scp[0][t] + scp[1][t] + scp[2][t] + scp[3][t];
}

// ---------------- K2: softmax over N=512 per batch (sums 2 col-partials) --------
__global__ void k_softmax(const float* __restrict__ part_sc, float* __restrict__ alpha) {
    __shared__ float red[16];
    const int b = blockIdx.x, t = threadIdx.x;     // 512 threads
    const int lane = t & 63, w = t >> 6;
    const int r = b * FEATN + t;
    float s = part_sc[r] + part_sc[BATCH * FEATN + r];
    float m = s;
#pragma unroll
    for (int d = 32; d; d >>= 1) m = fmaxf(m, __shfl_xor(m, d));
    if (lane == 0) red[w] = m;
    __syncthreads();
    if (t == 0) {
        float mm = red[0];
        for (int i = 1; i < 8; ++i) mm = fmaxf(mm, red[i]);
        red[8] = mm;
    }
    __syncthreads();
    float e = __expf(s - red[8]);
    float sum = e;
#pragma unroll
    for (int d = 32; d; d >>= 1) sum += __shfl_xor(sum, d);
    if (lane == 0) red[w] = sum;
    __syncthreads();
    if (t == 0) {
        float ss = 0.f;
        for (int i = 0; i < 8; ++i) ss += red[i];
        red[9] = 1.0f / ss;
    }
    __syncthreads();
    alpha[b * FEATN + t] = e * red[9];
}

// ---------------- K3a: partial att_feats over n-slices ----------------
__global__ void k_att_part(const float* __restrict__ feats, const float* __restrict__ alpha,
                           float* __restrict__ part) {
    const int b = blockIdx.x, fc = blockIdx.y, ns = blockIdx.z, t = threadIdx.x;
    const int f0 = fc * 1024 + t * 4;
    const float* fp = feats + (size_t)(b * FEATN + ns * 128) * FEATSZ + f0;
    const float* al = alpha + b * FEATN + ns * 128;
    float4 acc = {0.f, 0.f, 0.f, 0.f};
#pragma unroll 4
    for (int i = 0; i < 128; ++i) {
        float a = al[i];
        float4 v = *(const float4*)(fp + (size_t)i * FEATSZ);
        acc.x += a * v.x; acc.y += a * v.y; acc.z += a * v.z; acc.w += a * v.w;
    }
    *(float4*)(part + ((size_t)ns * BATCH + b) * FEATSZ + f0) = acc;
}

// ---------------- K3b: reduce 4 partials -> att_feats ----------------
__global__ void k_att_red(const float* __restrict__ part, float* __restrict__ out) {
    const int idx = (blockIdx.x * 256 + threadIdx.x) * 4;   // < 131072
    float4 s = *(const float4*)(part + idx);
#pragma unroll
    for (int z = 1; z < 4; ++z) {
        float4 v = *(const float4*)(part + (size_t)z * (BATCH * FEATSZ) + idx);
        s.x += v.x; s.y += v.y; s.z += v.z; s.w += v.w;
    }
    *(float4*)(out + idx) = s;
}

extern "C" void kernel_launch(void* const* d_in, const int* in_sizes, int n_in,
                              void* d_out, int out_size, void* d_ws, size_t ws_size,
                              hipStream_t stream) {
    const float* feats = (const float*)d_in[0];
    const float* key   = (const float*)d_in[1];
    const float* wh_w  = (const float*)d_in[2];
    const float* wh_b  = (const float*)d_in[3];
    const float* wv_w  = (const float*)d_in[4];
    const float* wv_b  = (const float*)d_in[5];
    const float* wa_w  = (const float*)d_in[6];

    float* out_att   = (float*)d_out;                 // 64*2048
    float* out_alpha = out_att + BATCH * FEATSZ;      // 64*512

    char* ws = (char*)d_ws;
    float* h            = (float*)(ws);               // 128 KB
    float* part_sc      = (float*)(ws + 131072);      // 2 x 128 KB
    unsigned short* wvb = (unsigned short*)(ws + 393216);  // 2 MB
    float* part         = (float*)(ws + 393216);      // 2 MB (reuses wvb after K1)

    hipLaunchKernelGGL(k_h,        dim3(8, 64),    dim3(256), 0, stream, key, wh_w, wh_b, h);
    hipLaunchKernelGGL(k_wvcvt,    dim3(4096),     dim3(256), 0, stream, wv_w, wvb);
    hipLaunchKernelGGL(k_scores,   dim3(256),      dim3(512), 0, stream, feats, wvb, h, wv_b, wa_w, part_sc);
    hipLaunchKernelGGL(k_softmax,  dim3(64),       dim3(512), 0, stream, part_sc, out_alpha);
    hipLaunchKernelGGL(k_att_part, dim3(64, 2, 4), dim3(256), 0, stream, feats, out_alpha, part);
    hipLaunchKernelGGL(k_att_red,  dim3(128),      dim3(256), 0, stream, part, out_att);
}